// Round 1
// 1220.217 us; speedup vs baseline: 1.1391x; 1.1391x over previous
//
// ===========================================================================
// R14 — LDS-throughput attack: CO_REG=2 register co-blocking (48 FMA per ci
// vs 24, same x reads, b64 paired weight reads), register-double-buffered ci
// loop, XOR bank swizzle for stride-32B read configs, CI-split for the
// 128-in-channel stride-1 convs, and ALL 9 bna kernels fused into consumer
// convs (BN/ReLU/skip on input staging, BN-add on output side).
// ===========================================================================
#include <hip/hip_runtime.h>
#include <stdint.h>

#define F_WT     1
#define F_STATS  2
#define F_BIAS   4
#define F_INBN   8
#define F_INRELU 16
#define F_INB    32
#define F_INBBN  64
#define F_ADD    128
#define F_ADDBN  256

// ---------------------------------------------------------------------------
// Tiled conv, CO_REG=2 outputs/thread in channel dim.
// MODE 0: stride-1 (pad runtime), WT: ConvTranspose (I,O,K) flipped.
// MODE 1: stride-2 downsample K=2. MODE 2: stride-2 transposed upsample K=2.
// 256 thr = (COB/2) co-pair groups x LT l-groups, TLT=TL/LT outputs/thread/co.
// ---------------------------------------------------------------------------
template<int CI, int CO, int K, int MODE, int TL, int COB, int FLAGS>
__global__ __launch_bounds__(256)
void conv_rE(const float* __restrict__ xa, const float2* __restrict__ sca,
             const float* __restrict__ xb, const float2* __restrict__ scb,
             const float* __restrict__ w,  const float* __restrict__ bias,
             const float* __restrict__ addsrc, const float2* __restrict__ scadd,
             double* __restrict__ stats, float* __restrict__ yout,
             int Lin, int Lout, int pad, int cis, int wci)
{
    constexpr int CR   = 2;
    constexpr int NCG  = COB / CR;          // co-pair groups (16)
    constexpr int LT   = 256 / NCG;         // l groups (16)
    constexpr int TLT  = TL / LT;           // outputs per thread per co
    constexpr int SPAN = (MODE == 0) ? (TL + K - 1)
                       : (MODE == 1) ? ((TL - 1) * 2 + K)
                       : (TL / 2);
    constexpr int SPANP = (SPAN + 3) & ~3;
    constexpr int WN    = COB * CI * K;
    constexpr int XR    = (MODE == 0) ? (TLT + K - 1)
                        : (MODE == 1) ? ((TLT - 1) * 2 + K)
                        : (TLT / 2);
    constexpr int WR    = K * CR;
    // lane stride in bytes for the x read; 32B stride = 4-way quad conflict
    constexpr bool SWZ  = (MODE == 0 && TLT == 8) || (MODE == 1 && TLT == 4);

    __shared__ float xs[CI * SPANP];
    __shared__ float wl[WN];                // [ci][k][co_l]

    const int tid    = threadIdx.x;
    const int ltile  = blockIdx.x;
    const int n      = blockIdx.y;
    const int coBase = blockIdx.z * COB;

    // ---- weights -> LDS ----
    for (int i = tid; i < WN; i += 256) {
        int ci   = i / (K * COB);
        int rem  = i - ci * (K * COB);
        int k    = rem / COB;
        int co_l = rem - k * COB;
        int co   = coBase + co_l;
        int src;
        if (FLAGS & F_WT)   src = (ci * CO + co) * K + (K - 1 - k);
        else if (MODE == 2) src = (ci * CO + co) * K + k;
        else                src = (co * wci + ci) * K + k;
        wl[i] = w[src];
    }

    // ---- x -> LDS (fused BN / ReLU / dual-input add; zero-pad AFTER) ----
    int x0;
    if (MODE == 0)      x0 = ltile * TL - pad;
    else if (MODE == 1) x0 = ltile * TL * 2;
    else                x0 = ltile * (TL / 2);

    for (int i = tid; i < CI * SPAN; i += 256) {
        int ci = i / SPAN;
        int s  = i - ci * SPAN;
        int xl = x0 + s;
        float v = 0.f;
        if (xl >= 0 && xl < Lin) {
            size_t idx = ((size_t)n * cis + ci) * (size_t)Lin + xl;
            v = xa[idx];
            if (FLAGS & F_INBN)   { float2 t = sca[ci]; v = v * t.x + t.y; }
            if (FLAGS & F_INRELU) v = fmaxf(v, 0.f);
            if (FLAGS & F_INB) {
                float u = xb[idx];
                if (FLAGS & F_INBBN) { float2 t = scb[ci]; u = u * t.x + t.y; }
                v += u;
            }
        }
        int st = ci * SPANP + s;
        if (SWZ) st ^= (st >> 3) & 4;
        xs[st] = v;
    }
    __syncthreads();

    const int cog   = tid / LT;             // co-pair group
    const int lg    = tid % LT;             // l group (consecutive lanes)
    const int co0   = coBase + cog * CR;
    const int loOff = lg * TLT;
    const int xoff  = (MODE == 1) ? loOff * 2
                    : (MODE == 2) ? (loOff >> 1) : loOff;

    float acc[CR][TLT];
#pragma unroll
    for (int cr = 0; cr < CR; ++cr) {
        float b = (FLAGS & F_BIAS) ? bias[co0 + cr] : 0.f;
#pragma unroll
        for (int j = 0; j < TLT; ++j) acc[cr][j] = b;
    }

    float xA[XR], xB[XR], wA[WR], wB[WR];

    auto ldx = [&](float* dst, int c) {
        const int base = c * SPANP + xoff;
#pragma unroll
        for (int g = 0; g < XR; g += 4) {
            int pb = base + g;
            if (SWZ) pb ^= (pb >> 3) & 4;
            const float* p = &xs[pb];
            constexpr int GMAX = 4;
#pragma unroll
            for (int t = 0; t < GMAX; ++t)
                if (g + t < XR) dst[g + t] = p[t];
        }
    };
    auto ldw = [&](float* dst, int c) {
        const float* q = &wl[c * (K * COB) + cog * CR];
#pragma unroll
        for (int k = 0; k < K; ++k)
#pragma unroll
            for (int cr = 0; cr < CR; ++cr)
                dst[k * CR + cr] = q[k * COB + cr];
    };
    auto dofma = [&](const float* xv, const float* wv) {
        if (MODE == 2) {
#pragma unroll
            for (int j = 0; j < TLT; ++j)
#pragma unroll
                for (int cr = 0; cr < CR; ++cr)
                    acc[cr][j] += wv[(j & 1) * CR + cr] * xv[j >> 1];
        } else {
#pragma unroll
            for (int k = 0; k < K; ++k)
#pragma unroll
                for (int j = 0; j < TLT; ++j)
#pragma unroll
                    for (int cr = 0; cr < CR; ++cr)
                        acc[cr][j] += wv[k * CR + cr]
                                    * xv[((MODE == 1) ? 2 * j : j) + k];
        }
    };

    // ---- register-double-buffered ci loop (CI is even, >= 32) ----
    ldx(xA, 0); ldw(wA, 0);
    for (int ci = 0; ci + 2 < CI; ci += 2) {
        ldx(xB, ci + 1); ldw(wB, ci + 1);
        dofma(xA, wA);
        ldx(xA, ci + 2); ldw(wA, ci + 2);
        dofma(xB, wB);
    }
    ldx(xB, CI - 1); ldw(wB, CI - 1);
    dofma(xA, wA);
    dofma(xB, wB);

    // ---- epilogue: output-side add (opt BN), store, stats ----
    const int lo0 = ltile * TL + loOff;
#pragma unroll
    for (int cr = 0; cr < CR; ++cr) {
        size_t ob = ((size_t)n * CO + (co0 + cr)) * (size_t)Lout + lo0;
        if (FLAGS & F_ADD) {
            float2 t = (FLAGS & F_ADDBN) ? scadd[co0 + cr] : make_float2(1.f, 0.f);
#pragma unroll
            for (int j = 0; j < TLT; ++j) {
                float a = addsrc[ob + j];
                acc[cr][j] += (FLAGS & F_ADDBN) ? (a * t.x + t.y) : a;
            }
        }
#pragma unroll
        for (int j = 0; j < TLT; ++j) yout[ob + j] = acc[cr][j];
    }

    if (FLAGS & F_STATS) {
        float s1[CR], s2[CR];
#pragma unroll
        for (int cr = 0; cr < CR; ++cr) {
            s1[cr] = 0.f; s2[cr] = 0.f;
#pragma unroll
            for (int j = 0; j < TLT; ++j) {
                s1[cr] += acc[cr][j];
                s2[cr] += acc[cr][j] * acc[cr][j];
            }
        }
#pragma unroll
        for (int m = 1; m < LT; m <<= 1) {
#pragma unroll
            for (int cr = 0; cr < CR; ++cr) {
                s1[cr] += __shfl_xor(s1[cr], m, 64);
                s2[cr] += __shfl_xor(s2[cr], m, 64);
            }
        }
        if ((tid & (LT - 1)) == 0) {
#pragma unroll
            for (int cr = 0; cr < CR; ++cr) {
                atomicAdd(&stats[co0 + cr],      (double)s1[cr]);
                atomicAdd(&stats[CO + co0 + cr], (double)s2[cr]);
            }
        }
    }
}

// ---------------------------------------------------------------------------
__global__ void bnp_rD(const double* __restrict__ stats,
                       const float* __restrict__ g, const float* __restrict__ be,
                       float2* __restrict__ sc, int C, double invNL)
{
    int c = threadIdx.x;
    if (c >= C) return;
    double mu  = stats[c] * invNL;
    double var = stats[C + c] * invNL - mu * mu;
    double rs  = 1.0 / sqrt(var + 1e-5);
    double gv  = (double)g[c] * rs;
    double bv  = (double)be[c] - mu * gv;
    sc[c] = make_float2((float)gv, (float)bv);
}

// ---------------------------------------------------------------------------
// VQ: 512 blocks x 256 thr; 64 rows/block, 4 lanes/row split over dims
// (16/lane in regs). Padded codebook stride 68 -> conflict-free b128.
// ---------------------------------------------------------------------------
__global__ __launch_bounds__(256)
void vq_rD(const float* __restrict__ z, const float* __restrict__ emb,
           float* __restrict__ hq, double* __restrict__ lossAcc)
{
    __shared__ float ws[128 * 68];
    const int tid = threadIdx.x;
    const int sub = tid & 3;
    const int r   = blockIdx.x * 64 + (tid >> 2);

    const float4* zp = (const float4*)(z + (size_t)r * 64 + sub * 16);
    float4 z0 = zp[0], z1 = zp[1], z2 = zp[2], z3 = zp[3];

    float best = 3.4e38f;
    int   bj   = 0;
    for (int c0 = 0; c0 < 512; c0 += 128) {
        __syncthreads();
        for (int i = tid; i < 128 * 16; i += 256) {
            int j = i >> 4, q = i & 15;
            ((float4*)ws)[j * 17 + q] = ((const float4*)(emb + c0 * 64))[i];
        }
        __syncthreads();
        for (int j = 0; j < 128; ++j) {
            const float4* wp = (const float4*)&ws[j * 68 + sub * 16];
            float4 w0 = wp[0], w1 = wp[1], w2 = wp[2], w3 = wp[3];
            float d = 0.f, t;
            t = z0.x - w0.x; d += t * t;  t = z0.y - w0.y; d += t * t;
            t = z0.z - w0.z; d += t * t;  t = z0.w - w0.w; d += t * t;
            t = z1.x - w1.x; d += t * t;  t = z1.y - w1.y; d += t * t;
            t = z1.z - w1.z; d += t * t;  t = z1.w - w1.w; d += t * t;
            t = z2.x - w2.x; d += t * t;  t = z2.y - w2.y; d += t * t;
            t = z2.z - w2.z; d += t * t;  t = z2.w - w2.w; d += t * t;
            t = z3.x - w3.x; d += t * t;  t = z3.y - w3.y; d += t * t;
            t = z3.z - w3.z; d += t * t;  t = z3.w - w3.w; d += t * t;
            d += __shfl_xor(d, 1, 64);
            d += __shfl_xor(d, 2, 64);
            if (d < best) { best = d; bj = c0 + j; }
        }
    }

    const float4* ep = (const float4*)(emb + (size_t)bj * 64 + sub * 16);
    float4* hp = (float4*)(hq + (size_t)r * 64 + sub * 16);
    hp[0] = ep[0]; hp[1] = ep[1]; hp[2] = ep[2]; hp[3] = ep[3];

    float s = (sub == 0) ? best : 0.f;
#pragma unroll
    for (int m = 1; m < 64; m <<= 1) s += __shfl_xor(s, m, 64);
    if ((tid & 63) == 0) atomicAdd(lossAcc, (double)s);
}

__global__ void zd_rD(double* p, int n) {
    int i = blockIdx.x * 256 + threadIdx.x;
    if (i < n) p[i] = 0.0;
}

__global__ void wsguard_rD(float* p, int n) {
    int i = blockIdx.x * 256 + threadIdx.x;
    if (i < n) p[i] = 1000.0f;
}

__global__ void lossfin_rD(const double* acc, float* out) {
    float m = (float)(acc[0] * (1.0 / 32768.0));
    out[2097152] = m;   // commit_loss
    out[2097153] = m;   // vq_loss
}

extern "C" void kernel_launch(void* const* d_in, const int* in_sizes, int n_in,
                              void* d_out, int out_size, void* d_ws, size_t ws_size,
                              hipStream_t stream)
{
    const size_t NEED = (size_t)3 * 4194304 * 4 + 2305 * 8 + 1152 * 8 + 64;
    if (ws_size < NEED) {
        wsguard_rD<<<dim3((out_size + 255) / 256), 256, 0, stream>>>((float*)d_out, out_size);
        return;
    }

    const float* x        = (const float*)d_in[0];
    const float* w_conv   = (const float*)d_in[1];
    const float* b_conv   = (const float*)d_in[2];
    const float* g_conv   = (const float*)d_in[3];
    const float* be_conv  = (const float*)d_in[4];
    const float* w_r1     = (const float*)d_in[5];
    const float* b_r1     = (const float*)d_in[6];
    const float* g_r1     = (const float*)d_in[7];
    const float* be_r1    = (const float*)d_in[8];
    const float* w_ds1    = (const float*)d_in[9];
    const float* b_ds1    = (const float*)d_in[10];
    const float* w_r2     = (const float*)d_in[11];
    const float* b_r2     = (const float*)d_in[12];
    const float* g_r2     = (const float*)d_in[13];
    const float* be_r2    = (const float*)d_in[14];
    const float* w_1to2   = (const float*)d_in[15];
    const float* w_ds2    = (const float*)d_in[16];
    const float* b_ds2    = (const float*)d_in[17];
    const float* embed_w  = (const float*)d_in[18];
    const float* w_us2    = (const float*)d_in[19];
    const float* b_us2    = (const float*)d_in[20];
    const float* w_dr2    = (const float*)d_in[21];
    const float* b_dr2    = (const float*)d_in[22];
    const float* g_dr2    = (const float*)d_in[23];
    const float* be_dr2   = (const float*)d_in[24];
    const float* w_2to1   = (const float*)d_in[25];
    const float* w_us1    = (const float*)d_in[26];
    const float* b_us1    = (const float*)d_in[27];
    const float* w_dr1    = (const float*)d_in[28];
    const float* b_dr1    = (const float*)d_in[29];
    const float* g_dr1    = (const float*)d_in[30];
    const float* be_dr1   = (const float*)d_in[31];
    const float* w_deconv = (const float*)d_in[32];
    const float* b_deconv = (const float*)d_in[33];

    float* out = (float*)d_out;

    float*  B0 = (float*)d_ws;
    float*  B1 = B0 + 4194304;
    float*  B2 = B1 + 4194304;
    double* SD = (double*)(B2 + 4194304);
    double* lossAcc = SD + 9 * 256;
    float2* SC = (float2*)(SD + 2305);

    const int N = 64;
    const double i64k = 1.0 / 65536.0;
    const double i32k = 1.0 / 32768.0;
    const float2* NOSC = nullptr;
    const float*  NOP  = nullptr;

    zd_rD<<<dim3(10), 256, 0, stream>>>(SD, 9 * 256 + 1);

    // ---- encoder ----
    // conv1: x -> B0 (raw), stats0
    conv_rE<32,64,7,0,128,32, F_BIAS|F_STATS>
        <<<dim3(8, N, 2), 256, 0, stream>>>(x, NOSC, NOP, NOSC, w_conv, b_conv,
            NOP, NOSC, SD+0*256, B0, 1024, 1024, 3, 32, 32);
    bnp_rD<<<1, 128, 0, stream>>>(SD+0*256, g_conv, be_conv, SC+0*128, 64, i64k);

    // r1#1: bn0(B0) -> conv -> B1, stats1
    conv_rE<64,64,3,0,128,32, F_BIAS|F_STATS|F_INBN>
        <<<dim3(8, N, 2), 256, 0, stream>>>(B0, SC+0*128, NOP, NOSC, w_r1, b_r1,
            NOP, NOSC, SD+1*256, B1, 1024, 1024, 1, 64, 64);
    bnp_rD<<<1, 128, 0, stream>>>(SD+1*256, g_r1, be_r1, SC+1*128, 64, i64k);

    // r1#2: relu(bn1(B1)) -> conv -> B2, stats2
    conv_rE<64,64,3,0,128,32, F_BIAS|F_STATS|F_INBN|F_INRELU>
        <<<dim3(8, N, 2), 256, 0, stream>>>(B1, SC+1*128, NOP, NOSC, w_r1+12288, b_r1+64,
            NOP, NOSC, SD+2*256, B2, 1024, 1024, 1, 64, 64);
    bnp_rD<<<1, 128, 0, stream>>>(SD+2*256, g_r1+64, be_r1+64, SC+2*128, 64, i64k);

    // r1#3: relu(bn2(B2)) -> conv -> B1, stats3
    conv_rE<64,64,3,0,128,32, F_BIAS|F_STATS|F_INBN|F_INRELU>
        <<<dim3(8, N, 2), 256, 0, stream>>>(B2, SC+2*128, NOP, NOSC, w_r1+24576, b_r1+128,
            NOP, NOSC, SD+3*256, B1, 1024, 1024, 1, 64, 64);
    bnp_rD<<<1, 128, 0, stream>>>(SD+3*256, g_r1+128, be_r1+128, SC+3*128, 64, i64k);

    // ds1: input = bn3(B1) + bn0(B0)  -> stride-2 conv -> B2
    conv_rE<64,64,2,1,64,32, F_BIAS|F_INBN|F_INB|F_INBBN>
        <<<dim3(8, N, 2), 256, 0, stream>>>(B1, SC+3*128, B0, SC+0*128, w_ds1, b_ds1,
            NOP, NOSC, nullptr, B2, 1024, 512, 0, 64, 64);

    // r2: B2 raw -> conv -> B1, stats4
    conv_rE<64,128,3,0,128,32, F_BIAS|F_STATS>
        <<<dim3(4, N, 4), 256, 0, stream>>>(B2, NOSC, NOP, NOSC, w_r2, b_r2,
            NOP, NOSC, SD+4*256, B1, 512, 512, 1, 64, 64);
    bnp_rD<<<1, 128, 0, stream>>>(SD+4*256, g_r2, be_r2, SC+4*128, 128, i32k);

    // 1to2: conv(B2,w_1to2) + bn4(B1) -> B0
    conv_rE<64,128,1,0,128,32, F_ADD|F_ADDBN>
        <<<dim3(4, N, 4), 256, 0, stream>>>(B2, NOSC, NOP, NOSC, w_1to2, NOP,
            B1, SC+4*128, nullptr, B0, 512, 512, 0, 64, 64);

    // ds2: B0 -> stride-2 conv -> B1
    conv_rE<128,128,2,1,32,32, F_BIAS>
        <<<dim3(8, N, 4), 256, 0, stream>>>(B0, NOSC, NOP, NOSC, w_ds2, b_ds2,
            NOP, NOSC, nullptr, B1, 512, 256, 0, 128, 128);

    // ---- vector quantization ----
    vq_rD<<<dim3(512), 256, 0, stream>>>(B1, embed_w, B2, lossAcc);
    lossfin_rD<<<1, 1, 0, stream>>>(lossAcc, out);

    // ---- decoder ----
    // us2: B2(hq) -> transposed stride-2 -> B0
    conv_rE<128,128,2,2,128,32, F_BIAS>
        <<<dim3(4, N, 4), 256, 0, stream>>>(B2, NOSC, NOP, NOSC, w_us2, b_us2,
            NOP, NOSC, nullptr, B0, 256, 512, 0, 128, 128);

    // dr2 (CI=128 split into 2x64): a = ci 0..63 + bias -> B1
    conv_rE<64,64,3,0,128,32, F_WT|F_BIAS>
        <<<dim3(4, N, 2), 256, 0, stream>>>(B0, NOSC, NOP, NOSC, w_dr2, b_dr2,
            NOP, NOSC, nullptr, B1, 512, 512, 1, 128, 64);
    //            b = ci 64..127, accumulate into B1, stats5
    conv_rE<64,64,3,0,128,32, F_WT|F_STATS|F_ADD>
        <<<dim3(4, N, 2), 256, 0, stream>>>(B0 + (size_t)64*512, NOSC, NOP, NOSC,
            w_dr2 + 64*64*3, NOP, B1, NOSC, SD+5*256, B1, 512, 512, 1, 128, 64);
    bnp_rD<<<1, 128, 0, stream>>>(SD+5*256, g_dr2, be_dr2, SC+5*128, 64, i32k);

    // 2to1 (CI=128 split): a = conv(ci 0..63) + bn5(B1) -> B2
    conv_rE<64,64,1,0,128,32, F_ADD|F_ADDBN>
        <<<dim3(4, N, 2), 256, 0, stream>>>(B0, NOSC, NOP, NOSC, w_2to1, NOP,
            B1, SC+5*128, nullptr, B2, 512, 512, 0, 128, 128);
    //              b = conv(ci 64..127) accumulate -> B2
    conv_rE<64,64,1,0,128,32, F_ADD>
        <<<dim3(4, N, 2), 256, 0, stream>>>(B0 + (size_t)64*512, NOSC, NOP, NOSC,
            w_2to1 + 64, NOP, B2, NOSC, nullptr, B2, 512, 512, 0, 128, 128);

    // us1: B2 -> transposed stride-2 -> B0 (t, kept raw for final skip)
    conv_rE<64,64,2,2,128,32, F_BIAS>
        <<<dim3(8, N, 2), 256, 0, stream>>>(B2, NOSC, NOP, NOSC, w_us1, b_us1,
            NOP, NOSC, nullptr, B0, 512, 1024, 0, 64, 64);

    // dr1#1: B0 raw -> convT -> B1, stats6
    conv_rE<64,64,3,0,128,32, F_WT|F_BIAS|F_STATS>
        <<<dim3(8, N, 2), 256, 0, stream>>>(B0, NOSC, NOP, NOSC, w_dr1, b_dr1,
            NOP, NOSC, SD+6*256, B1, 1024, 1024, 1, 64, 64);
    bnp_rD<<<1, 128, 0, stream>>>(SD+6*256, g_dr1, be_dr1, SC+6*128, 64, i64k);

    // dr1#2: relu(bn6(B1)) -> convT -> B2, stats7
    conv_rE<64,64,3,0,128,32, F_WT|F_BIAS|F_STATS|F_INBN|F_INRELU>
        <<<dim3(8, N, 2), 256, 0, stream>>>(B1, SC+6*128, NOP, NOSC, w_dr1+12288, b_dr1+64,
            NOP, NOSC, SD+7*256, B2, 1024, 1024, 1, 64, 64);
    bnp_rD<<<1, 128, 0, stream>>>(SD+7*256, g_dr1+64, be_dr1+64, SC+7*128, 64, i64k);

    // dr1#3: relu(bn7(B2)) -> convT -> B1, stats8
    conv_rE<64,64,3,0,128,32, F_WT|F_BIAS|F_STATS|F_INBN|F_INRELU>
        <<<dim3(8, N, 2), 256, 0, stream>>>(B2, SC+7*128, NOP, NOSC, w_dr1+24576, b_dr1+128,
            NOP, NOSC, SD+8*256, B1, 1024, 1024, 1, 64, 64);
    bnp_rD<<<1, 128, 0, stream>>>(SD+8*256, g_dr1+128, be_dr1+128, SC+8*128, 64, i64k);

    // deconv: input = bn8(B1) + B0 raw -> convT K=7 -> out
    conv_rE<64,32,7,0,64,32, F_WT|F_BIAS|F_INBN|F_INB>
        <<<dim3(16, N, 1), 256, 0, stream>>>(B1, SC+8*128, B0, NOSC, w_deconv, b_deconv,
            NOP, NOSC, nullptr, out, 1024, 1024, 3, 64, 64);
}